// Round 7
// baseline (21384.691 us; speedup 1.0000x reference)
//
#include <hip/hip_runtime.h>

// RadialNCA — XLA-f32 bit-replication (PASSED R6 at absmax=0.015625).
// NUMERICS FROZEN: per-output op sequence must stay bit-identical:
//   mm1: ascending-k single-acc FMA over (kh,kw,c), c fastest; + b1 add
//   tanh: Eigen/XLA fast-tanh rational (clamp 7.905..., IEEE f32 div, select)
//   mm2: ascending-n single-acc FMA; + b2; 0.5f*delta; + s0; clip
// R7: occupancy fix only — 2 px/thread -> 1024 blocks = 4 blocks/CU
// (16 waves/CU vs 8). Same op sequence per pixel => bit-identical result.

#define BATCH 8
#define HGT 256
#define WID 256
#define NHID 256
#define ALPHA 0.5f

// ws layout (floats): [0, 6291456) state ping buffer; then W1^T (+b1), W2
#define WS_W1T_OFF (BATCH * HGT * WID * 3)
#define WS_W2_OFF  (WS_W1T_OFF + 28 * NHID)

// Exact XLA/Eigen generic_fast_tanh_float
__device__ __forceinline__ float tanh_xla(float x) {
    const float cl = 7.90531110763549805f;
    float xc = fminf(fmaxf(x, -cl), cl);
    float x2 = xc * xc;
    float p = fmaf(x2, -2.76076847742355e-16f, 2.00018790482477e-13f);
    p = fmaf(x2, p, -8.60467152213735e-11f);
    p = fmaf(x2, p, 5.12229709037114e-08f);
    p = fmaf(x2, p, 1.48572235717979e-05f);
    p = fmaf(x2, p, 6.37261928875436e-04f);
    p = fmaf(x2, p, 4.89352455891786e-03f);
    p = xc * p;
    float q = fmaf(x2, 1.19825839466702e-06f, 1.18534705686654e-04f);
    q = fmaf(x2, q, 2.26843463243900e-03f);
    q = fmaf(x2, q, 4.89352518554385e-03f);
    float r = p / q;                       // IEEE f32 div (no fast-math)
    return (fabsf(x) < 0.0004f) ? x : r;
}

// w1t[n][k] = W1[k][n] for k<27; w1t[n][27] = b1[n]; then W2
__global__ __launch_bounds__(256) void nca_prep(const float* __restrict__ W1,
                                                const float* __restrict__ b1,
                                                const float* __restrict__ W2,
                                                float* __restrict__ ws) {
    int n = threadIdx.x;
    float* w1t = ws + WS_W1T_OFF;
#pragma unroll
    for (int k = 0; k < 27; ++k) w1t[n * 28 + k] = W1[k * NHID + n];
    w1t[n * 28 + 27] = b1[n];
    ws[WS_W2_OFF + n] = W2[n];
}

__global__ __launch_bounds__(256) void nca_step(const float* __restrict__ sin,
                                                float* __restrict__ sout,
                                                const float* __restrict__ ws,
                                                const float* __restrict__ b2p) {
    __shared__ float lw1[NHID * 28];
    __shared__ float lw2[NHID];
    const int tid = threadIdx.x;

    const float* w1t = ws + WS_W1T_OFF;
#pragma unroll
    for (int i = 0; i < 28; ++i) lw1[i * 256 + tid] = w1t[i * 256 + tid];
    lw2[tid] = ws[WS_W2_OFF + tid];
    __syncthreads();

    // thread -> (b, y, x0): 2 horizontally adjacent pixels
    const int gid = blockIdx.x * 256 + tid;   // 0 .. 262143
    const int xq = gid & 127;                 // x0 / 2
    const int y  = (gid >> 7) & 255;
    const int b  = gid >> 15;
    const int x0 = xq * 2;

    // neighborhood rows y-1..y+1, cols x0-1..x0+2, 3 channels
    float X[3][4][3];
#pragma unroll
    for (int r = 0; r < 3; ++r) {
        const int yy = y + r - 1;
        const bool yok = (yy >= 0) && (yy < HGT);
        const float* rowp = sin + (((long)b * HGT + (yok ? yy : 0)) * WID) * 3;
#pragma unroll
        for (int cc = 0; cc < 4; ++cc) {
            const int xx = x0 + cc - 1;
            const bool ok = yok && (xx >= 0) && (xx < WID);
            if (ok) {
                X[r][cc][0] = rowp[xx * 3 + 0];
                X[r][cc][1] = rowp[xx * 3 + 1];
                X[r][cc][2] = rowp[xx * 3 + 2];
            } else {
                X[r][cc][0] = 0.f; X[r][cc][1] = 0.f; X[r][cc][2] = 0.f;
            }
        }
    }

    float delta[2] = {0.f, 0.f};

    for (int n = 0; n < NHID; ++n) {
        float w[28];
        const float4* wp = (const float4*)&lw1[n * 28];
#pragma unroll
        for (int q = 0; q < 7; ++q) ((float4*)w)[q] = wp[q];
        const float w2n = lw2[n];

#pragma unroll
        for (int p = 0; p < 2; ++p) {
            float acc = 0.f;
#pragma unroll
            for (int kh = 0; kh < 3; ++kh)
#pragma unroll
                for (int kw = 0; kw < 3; ++kw)
#pragma unroll
                    for (int c = 0; c < 3; ++c)
                        acc = fmaf(X[kh][kw + p][c], w[(kh * 3 + kw) * 3 + c], acc);
            acc = acc + w[27];                  // + b1[n]
            const float h = tanh_xla(acc);
            delta[p] = fmaf(h, w2n, delta[p]);  // mm2: ascending-n FMA
        }
    }

    const float b2v = b2p[0];
    float* op = sout + (((long)b * HGT + y) * WID + x0) * 3;
#pragma unroll
    for (int p = 0; p < 2; ++p) {
        const float s0 = X[1][p + 1][0];
        const float d  = delta[p] + b2v;        // + b2 (zero)
        const float td = ALPHA * d;             // exact (exponent shift)
        float pat = s0 + td;                    // f32 add
        pat = fminf(fmaxf(pat, 0.f), 1.f);      // clip
        op[p * 3 + 0] = pat;
        op[p * 3 + 1] = X[1][p + 1][1];
        op[p * 3 + 2] = X[1][p + 1][2];
    }
}

extern "C" void kernel_launch(void* const* d_in, const int* in_sizes, int n_in,
                              void* d_out, int out_size, void* d_ws, size_t ws_size,
                              hipStream_t stream) {
    const float* state = (const float*)d_in[0];
    const float* W1    = (const float*)d_in[1];
    const float* b1    = (const float*)d_in[2];
    const float* W2    = (const float*)d_in[3];
    const float* b2    = (const float*)d_in[4];

    float* ws_state = (float*)d_ws;
    float* out      = (float*)d_out;

    nca_prep<<<1, 256, 0, stream>>>(W1, b1, W2, ws_state);

    const int nblocks = (BATCH * HGT * (WID / 2)) / 256;   // 1024

    for (int t = 0; t < 128; ++t) {
        const float* in  = (t == 0) ? state : (((t - 1) & 1) ? out : ws_state);
        float*       dst = (t & 1) ? out : ws_state;
        nca_step<<<nblocks, 256, 0, stream>>>(in, dst, ws_state, b2);
    }
}

// Round 8
// 20608.722 us; speedup vs baseline: 1.0377x; 1.0377x over previous
//
#include <hip/hip_runtime.h>

// RadialNCA — XLA-f32 bit-replication (PASSES at absmax=0.015625).
// NUMERICS FROZEN: per-output op sequence must stay bit-identical:
//   mm1: ascending-k single-acc FMA over (kh,kw,c), c fastest; + b1 add
//   tanh: Eigen/XLA fast-tanh rational (clamp 7.905..., IEEE f32 div, select)
//   mm2: ascending-n single-acc FMA; + b2; 0.5f*delta; + s0; clip
//
// R8: weights off the LDS pipe. The per-n weight column address is
// wave-uniform -> read from GLOBAL via uniform index so the compiler
// emits s_load (scalar pipe, SGPR operands). No LDS at all. 1 px/thread
// -> 2048 blocks = 32 waves/CU (full occupancy cap).

#define BATCH 8
#define HGT 256
#define WID 256
#define NHID 256
#define ALPHA 0.5f

// ws layout (floats): [0, 6291456) state ping buffer; then W1^T (+b1), W2
#define WS_W1T_OFF (BATCH * HGT * WID * 3)
#define WS_W2_OFF  (WS_W1T_OFF + 28 * NHID)

// Exact XLA/Eigen generic_fast_tanh_float
__device__ __forceinline__ float tanh_xla(float x) {
    const float cl = 7.90531110763549805f;
    float xc = fminf(fmaxf(x, -cl), cl);
    float x2 = xc * xc;
    float p = fmaf(x2, -2.76076847742355e-16f, 2.00018790482477e-13f);
    p = fmaf(x2, p, -8.60467152213735e-11f);
    p = fmaf(x2, p, 5.12229709037114e-08f);
    p = fmaf(x2, p, 1.48572235717979e-05f);
    p = fmaf(x2, p, 6.37261928875436e-04f);
    p = fmaf(x2, p, 4.89352455891786e-03f);
    p = xc * p;
    float q = fmaf(x2, 1.19825839466702e-06f, 1.18534705686654e-04f);
    q = fmaf(x2, q, 2.26843463243900e-03f);
    q = fmaf(x2, q, 4.89352518554385e-03f);
    float r = p / q;                       // IEEE f32 div (no fast-math)
    return (fabsf(x) < 0.0004f) ? x : r;
}

// w1t[n][k] = W1[k][n] for k<27; w1t[n][27] = b1[n]; then W2
__global__ __launch_bounds__(256) void nca_prep(const float* __restrict__ W1,
                                                const float* __restrict__ b1,
                                                const float* __restrict__ W2,
                                                float* __restrict__ ws) {
    int n = threadIdx.x;
    float* w1t = ws + WS_W1T_OFF;
#pragma unroll
    for (int k = 0; k < 27; ++k) w1t[n * 28 + k] = W1[k * NHID + n];
    w1t[n * 28 + 27] = b1[n];
    ws[WS_W2_OFF + n] = W2[n];
}

__global__ __launch_bounds__(256) void nca_step(const float* __restrict__ sin,
                                                float* __restrict__ sout,
                                                const float* __restrict__ w1t,
                                                const float* __restrict__ w2,
                                                const float* __restrict__ b2p) {
    const int gid = blockIdx.x * 256 + threadIdx.x;   // 0 .. 524287 (one pixel)
    const int x = gid & 255;
    const int y = (gid >> 8) & 255;
    const int b = gid >> 16;

    // 3x3x3 neighborhood in registers
    float X[3][3][3];
#pragma unroll
    for (int r = 0; r < 3; ++r) {
        const int yy = y + r - 1;
        const bool yok = (yy >= 0) && (yy < HGT);
        const float* rowp = sin + (((long)b * HGT + (yok ? yy : 0)) * WID) * 3;
#pragma unroll
        for (int cc = 0; cc < 3; ++cc) {
            const int xx = x + cc - 1;
            const bool ok = yok && (xx >= 0) && (xx < WID);
            if (ok) {
                X[r][cc][0] = rowp[xx * 3 + 0];
                X[r][cc][1] = rowp[xx * 3 + 1];
                X[r][cc][2] = rowp[xx * 3 + 2];
            } else {
                X[r][cc][0] = 0.f; X[r][cc][1] = 0.f; X[r][cc][2] = 0.f;
            }
        }
    }

    const float4* __restrict__ wq = (const float4*)w1t;   // 7 float4 per n

    float delta = 0.f;

    for (int n = 0; n < NHID; ++n) {
        // wave-uniform index -> scalar loads (s_load_dwordx4), SGPR operands
        float w[28];
#pragma unroll
        for (int q = 0; q < 7; ++q) ((float4*)w)[q] = wq[n * 7 + q];
        const float w2n = w2[n];

        float acc = 0.f;
#pragma unroll
        for (int kh = 0; kh < 3; ++kh)
#pragma unroll
            for (int kw = 0; kw < 3; ++kw)
#pragma unroll
                for (int c = 0; c < 3; ++c)
                    acc = fmaf(X[kh][kw][c], w[(kh * 3 + kw) * 3 + c], acc);
        acc = acc + w[27];                  // + b1[n]
        const float h = tanh_xla(acc);
        delta = fmaf(h, w2n, delta);        // mm2: ascending-n FMA
    }

    const float b2v = b2p[0];
    float* op = sout + (long)gid * 3;
    const float s0 = X[1][1][0];
    const float d  = delta + b2v;           // + b2 (zero)
    const float td = ALPHA * d;             // exact (exponent shift)
    float pat = s0 + td;                    // f32 add
    pat = fminf(fmaxf(pat, 0.f), 1.f);      // clip
    op[0] = pat;
    op[1] = X[1][1][1];
    op[2] = X[1][1][2];
}

extern "C" void kernel_launch(void* const* d_in, const int* in_sizes, int n_in,
                              void* d_out, int out_size, void* d_ws, size_t ws_size,
                              hipStream_t stream) {
    const float* state = (const float*)d_in[0];
    const float* W1    = (const float*)d_in[1];
    const float* b1    = (const float*)d_in[2];
    const float* W2    = (const float*)d_in[3];
    const float* b2    = (const float*)d_in[4];

    float* ws_state = (float*)d_ws;
    float* w1t      = ws_state + WS_W1T_OFF;
    float* w2c      = ws_state + WS_W2_OFF;
    float* out      = (float*)d_out;

    nca_prep<<<1, 256, 0, stream>>>(W1, b1, W2, ws_state);

    const int nblocks = (BATCH * HGT * WID) / 256;   // 2048

    for (int t = 0; t < 128; ++t) {
        const float* in  = (t == 0) ? state : (((t - 1) & 1) ? out : ws_state);
        float*       dst = (t & 1) ? out : ws_state;
        nca_step<<<nblocks, 256, 0, stream>>>(in, dst, w1t, w2c, b2);
    }
}

// Round 9
// 20408.267 us; speedup vs baseline: 1.0478x; 1.0098x over previous
//
#include <hip/hip_runtime.h>

// RadialNCA — XLA-f32 bit-replication (PASSES at absmax=0.015625).
// NUMERICS FROZEN: per-output op sequence must stay bit-identical:
//   mm1: ascending-k single-acc FMA over (kh,kw,c), c fastest; + b1 add
//   tanh: Eigen/XLA fast-tanh rational (clamp 7.905..., IEEE f32 div, select)
//   mm2: ascending-n single-acc FMA; + b2; 0.5f*delta; + s0; clip
//
// R9: R8 (scalar-pipe weights, no LDS, 1px/thread) + register fix.
// R8's VGPR=20 showed the RA sank the 27 X loads into the n-loop
// (27 re-loads x 256 n). __launch_bounds__(256,4) caps occupancy chase
// (VGPR budget 128) so X stays resident; weights as named float4 SSA
// values -> SGPRs; #pragma unroll 2 for chain ILP.

#define BATCH 8
#define HGT 256
#define WID 256
#define NHID 256
#define ALPHA 0.5f

// ws layout (floats): [0, 6291456) state ping buffer; then W1^T (+b1), W2
#define WS_W1T_OFF (BATCH * HGT * WID * 3)
#define WS_W2_OFF  (WS_W1T_OFF + 28 * NHID)

// Exact XLA/Eigen generic_fast_tanh_float
__device__ __forceinline__ float tanh_xla(float x) {
    const float cl = 7.90531110763549805f;
    float xc = fminf(fmaxf(x, -cl), cl);
    float x2 = xc * xc;
    float p = fmaf(x2, -2.76076847742355e-16f, 2.00018790482477e-13f);
    p = fmaf(x2, p, -8.60467152213735e-11f);
    p = fmaf(x2, p, 5.12229709037114e-08f);
    p = fmaf(x2, p, 1.48572235717979e-05f);
    p = fmaf(x2, p, 6.37261928875436e-04f);
    p = fmaf(x2, p, 4.89352455891786e-03f);
    p = xc * p;
    float q = fmaf(x2, 1.19825839466702e-06f, 1.18534705686654e-04f);
    q = fmaf(x2, q, 2.26843463243900e-03f);
    q = fmaf(x2, q, 4.89352518554385e-03f);
    float r = p / q;                       // IEEE f32 div (no fast-math)
    return (fabsf(x) < 0.0004f) ? x : r;
}

// w1t[n][k] = W1[k][n] for k<27; w1t[n][27] = b1[n]; then W2
__global__ __launch_bounds__(256) void nca_prep(const float* __restrict__ W1,
                                                const float* __restrict__ b1,
                                                const float* __restrict__ W2,
                                                float* __restrict__ ws) {
    int n = threadIdx.x;
    float* w1t = ws + WS_W1T_OFF;
#pragma unroll
    for (int k = 0; k < 27; ++k) w1t[n * 28 + k] = W1[k * NHID + n];
    w1t[n * 28 + 27] = b1[n];
    ws[WS_W2_OFF + n] = W2[n];
}

__global__ __launch_bounds__(256, 4) void nca_step(const float* __restrict__ sin,
                                                   float* __restrict__ sout,
                                                   const float* __restrict__ w1t,
                                                   const float* __restrict__ w2,
                                                   const float* __restrict__ b2p) {
    const int gid = blockIdx.x * 256 + threadIdx.x;   // one pixel per thread
    const int x = gid & 255;
    const int y = (gid >> 8) & 255;
    const int b = gid >> 16;

    // 3x3x3 neighborhood in registers
    float X[3][3][3];
#pragma unroll
    for (int r = 0; r < 3; ++r) {
        const int yy = y + r - 1;
        const bool yok = (yy >= 0) && (yy < HGT);
        const float* rowp = sin + (((long)b * HGT + (yok ? yy : 0)) * WID) * 3;
#pragma unroll
        for (int cc = 0; cc < 3; ++cc) {
            const int xx = x + cc - 1;
            const bool ok = yok && (xx >= 0) && (xx < WID);
            if (ok) {
                X[r][cc][0] = rowp[xx * 3 + 0];
                X[r][cc][1] = rowp[xx * 3 + 1];
                X[r][cc][2] = rowp[xx * 3 + 2];
            } else {
                X[r][cc][0] = 0.f; X[r][cc][1] = 0.f; X[r][cc][2] = 0.f;
            }
        }
    }

    const float4* __restrict__ wq = (const float4*)w1t;   // 7 float4 per n

    float delta = 0.f;

#pragma unroll 2
    for (int n = 0; n < NHID; ++n) {
        // wave-uniform address -> s_load_dwordx4; named SSA values stay in SGPRs
        const float4 w0 = wq[n * 7 + 0];
        const float4 w1 = wq[n * 7 + 1];
        const float4 w2v = wq[n * 7 + 2];
        const float4 w3 = wq[n * 7 + 3];
        const float4 w4 = wq[n * 7 + 4];
        const float4 w5 = wq[n * 7 + 5];
        const float4 w6 = wq[n * 7 + 6];
        const float w2n = w2[n];

        // mm1: ascending-k single-accumulator FMA, k=(kh*3+kw)*3+c, c fastest
        float acc = 0.f;
        acc = fmaf(X[0][0][0], w0.x, acc);   // k=0
        acc = fmaf(X[0][0][1], w0.y, acc);
        acc = fmaf(X[0][0][2], w0.z, acc);
        acc = fmaf(X[0][1][0], w0.w, acc);
        acc = fmaf(X[0][1][1], w1.x, acc);
        acc = fmaf(X[0][1][2], w1.y, acc);
        acc = fmaf(X[0][2][0], w1.z, acc);
        acc = fmaf(X[0][2][1], w1.w, acc);
        acc = fmaf(X[0][2][2], w2v.x, acc);
        acc = fmaf(X[1][0][0], w2v.y, acc);
        acc = fmaf(X[1][0][1], w2v.z, acc);
        acc = fmaf(X[1][0][2], w2v.w, acc);
        acc = fmaf(X[1][1][0], w3.x, acc);   // k=12 (center pattern)
        acc = fmaf(X[1][1][1], w3.y, acc);
        acc = fmaf(X[1][1][2], w3.z, acc);
        acc = fmaf(X[1][2][0], w3.w, acc);
        acc = fmaf(X[1][2][1], w4.x, acc);
        acc = fmaf(X[1][2][2], w4.y, acc);
        acc = fmaf(X[2][0][0], w4.z, acc);
        acc = fmaf(X[2][0][1], w4.w, acc);
        acc = fmaf(X[2][0][2], w5.x, acc);
        acc = fmaf(X[2][1][0], w5.y, acc);
        acc = fmaf(X[2][1][1], w5.z, acc);
        acc = fmaf(X[2][1][2], w5.w, acc);
        acc = fmaf(X[2][2][0], w6.x, acc);
        acc = fmaf(X[2][2][1], w6.y, acc);
        acc = fmaf(X[2][2][2], w6.z, acc);   // k=26
        acc = acc + w6.w;                    // + b1[n]
        const float h = tanh_xla(acc);
        delta = fmaf(h, w2n, delta);         // mm2: ascending-n FMA
    }

    const float b2v = b2p[0];
    float* op = sout + (long)gid * 3;
    const float s0 = X[1][1][0];
    const float d  = delta + b2v;           // + b2 (zero)
    const float td = ALPHA * d;             // exact (exponent shift)
    float pat = s0 + td;                    // f32 add
    pat = fminf(fmaxf(pat, 0.f), 1.f);      // clip
    op[0] = pat;
    op[1] = X[1][1][1];
    op[2] = X[1][1][2];
}

extern "C" void kernel_launch(void* const* d_in, const int* in_sizes, int n_in,
                              void* d_out, int out_size, void* d_ws, size_t ws_size,
                              hipStream_t stream) {
    const float* state = (const float*)d_in[0];
    const float* W1    = (const float*)d_in[1];
    const float* b1    = (const float*)d_in[2];
    const float* W2    = (const float*)d_in[3];
    const float* b2    = (const float*)d_in[4];

    float* ws_state = (float*)d_ws;
    float* w1t      = ws_state + WS_W1T_OFF;
    float* w2c      = ws_state + WS_W2_OFF;
    float* out      = (float*)d_out;

    nca_prep<<<1, 256, 0, stream>>>(W1, b1, W2, ws_state);

    const int nblocks = (BATCH * HGT * WID) / 256;   // 2048

    for (int t = 0; t < 128; ++t) {
        const float* in  = (t == 0) ? state : (((t - 1) & 1) ? out : ws_state);
        float*       dst = (t & 1) ? out : ws_state;
        nca_step<<<nblocks, 256, 0, stream>>>(in, dst, w1t, w2c, b2);
    }
}

// Round 10
// 18809.515 us; speedup vs baseline: 1.1369x; 1.0850x over previous
//
#include <hip/hip_runtime.h>

// RadialNCA — XLA-f32 bit-replication (PASSES at absmax=0.015625).
// NUMERICS FROZEN: per-output op sequence must stay bit-identical:
//   mm1: ascending-k single-acc FMA over (kh,kw,c), c fastest; + b1 add
//   tanh: Eigen/XLA fast-tanh rational (clamp 7.905..., IEEE f32 div, select)
//   mm2: ascending-n single-acc FMA; + b2; 0.5f*delta; + s0; clip
//
// R10: pin the neighborhood in ARCH VGPRs. R9's VGPR=24 + VALU@108% +
// 2x-floor time showed the RA kept X out of arch VGPRs (re-load/AGPR
// traffic doubling VALU ops). Fixes:
//   - amdgpu_waves_per_eu(4,4): occupancy pinned -> 128-VGPR budget
//   - asm "+v" keep-alive on each X element: no remat, no sinking
//   - 2 px/thread, 1024 blocks, scalar-pipe weights (s_load), no LDS

#define BATCH 8
#define HGT 256
#define WID 256
#define NHID 256
#define ALPHA 0.5f

// ws layout (floats): [0, 6291456) state ping buffer; then W1^T (+b1), W2
#define WS_W1T_OFF (BATCH * HGT * WID * 3)
#define WS_W2_OFF  (WS_W1T_OFF + 28 * NHID)

// Exact XLA/Eigen generic_fast_tanh_float
__device__ __forceinline__ float tanh_xla(float x) {
    const float cl = 7.90531110763549805f;
    float xc = fminf(fmaxf(x, -cl), cl);
    float x2 = xc * xc;
    float p = fmaf(x2, -2.76076847742355e-16f, 2.00018790482477e-13f);
    p = fmaf(x2, p, -8.60467152213735e-11f);
    p = fmaf(x2, p, 5.12229709037114e-08f);
    p = fmaf(x2, p, 1.48572235717979e-05f);
    p = fmaf(x2, p, 6.37261928875436e-04f);
    p = fmaf(x2, p, 4.89352455891786e-03f);
    p = xc * p;
    float q = fmaf(x2, 1.19825839466702e-06f, 1.18534705686654e-04f);
    q = fmaf(x2, q, 2.26843463243900e-03f);
    q = fmaf(x2, q, 4.89352518554385e-03f);
    float r = p / q;                       // IEEE f32 div (no fast-math)
    return (fabsf(x) < 0.0004f) ? x : r;
}

// w1t[n][k] = W1[k][n] for k<27; w1t[n][27] = b1[n]; then W2
__global__ __launch_bounds__(256) void nca_prep(const float* __restrict__ W1,
                                                const float* __restrict__ b1,
                                                const float* __restrict__ W2,
                                                float* __restrict__ ws) {
    int n = threadIdx.x;
    float* w1t = ws + WS_W1T_OFF;
#pragma unroll
    for (int k = 0; k < 27; ++k) w1t[n * 28 + k] = W1[k * NHID + n];
    w1t[n * 28 + 27] = b1[n];
    ws[WS_W2_OFF + n] = W2[n];
}

__global__ __launch_bounds__(256)
__attribute__((amdgpu_waves_per_eu(4, 4)))
void nca_step(const float* __restrict__ sin,
              float* __restrict__ sout,
              const float* __restrict__ w1t,
              const float* __restrict__ w2,
              const float* __restrict__ b2p) {
    const int tid = threadIdx.x;
    const int gid = blockIdx.x * 256 + tid;   // 0 .. 262143 (2 px each)
    const int xq = gid & 127;
    const int y  = (gid >> 7) & 255;
    const int b  = gid >> 15;
    const int x0 = xq * 2;

    // neighborhood rows y-1..y+1, cols x0-1..x0+2, 3 channels
    float X[3][4][3];
#pragma unroll
    for (int r = 0; r < 3; ++r) {
        const int yy = y + r - 1;
        const bool yok = (yy >= 0) && (yy < HGT);
        const float* rowp = sin + (((long)b * HGT + (yok ? yy : 0)) * WID) * 3;
#pragma unroll
        for (int cc = 0; cc < 4; ++cc) {
            const int xx = x0 + cc - 1;
            const bool ok = yok && (xx >= 0) && (xx < WID);
            if (ok) {
                X[r][cc][0] = rowp[xx * 3 + 0];
                X[r][cc][1] = rowp[xx * 3 + 1];
                X[r][cc][2] = rowp[xx * 3 + 2];
            } else {
                X[r][cc][0] = 0.f; X[r][cc][1] = 0.f; X[r][cc][2] = 0.f;
            }
        }
    }
    // Pin all 36 staged values in arch VGPRs; forbid remat/sinking.
#pragma unroll
    for (int r = 0; r < 3; ++r)
#pragma unroll
        for (int cc = 0; cc < 4; ++cc)
#pragma unroll
            for (int c = 0; c < 3; ++c)
                asm volatile("" : "+v"(X[r][cc][c]));

    const float4* __restrict__ wq = (const float4*)w1t;   // 7 float4 per n

    float delta0 = 0.f, delta1 = 0.f;

#pragma unroll 2
    for (int n = 0; n < NHID; ++n) {
        // wave-uniform -> s_load_dwordx4; named SSA values live in SGPRs
        const float4 w0 = wq[n * 7 + 0];
        const float4 w1 = wq[n * 7 + 1];
        const float4 w2v = wq[n * 7 + 2];
        const float4 w3 = wq[n * 7 + 3];
        const float4 w4 = wq[n * 7 + 4];
        const float4 w5 = wq[n * 7 + 5];
        const float4 w6 = wq[n * 7 + 6];
        const float w2n = w2[n];

        float wk[27] = {w0.x, w0.y, w0.z, w0.w, w1.x, w1.y, w1.z, w1.w,
                        w2v.x, w2v.y, w2v.z, w2v.w, w3.x, w3.y, w3.z, w3.w,
                        w4.x, w4.y, w4.z, w4.w, w5.x, w5.y, w5.z, w5.w,
                        w6.x, w6.y, w6.z};

#pragma unroll
        for (int p = 0; p < 2; ++p) {
            float acc = 0.f;
#pragma unroll
            for (int kh = 0; kh < 3; ++kh)
#pragma unroll
                for (int kw = 0; kw < 3; ++kw)
#pragma unroll
                    for (int c = 0; c < 3; ++c)
                        acc = fmaf(X[kh][kw + p][c], wk[(kh * 3 + kw) * 3 + c], acc);
            acc = acc + w6.w;                    // + b1[n]
            const float h = tanh_xla(acc);
            if (p == 0) delta0 = fmaf(h, w2n, delta0);
            else        delta1 = fmaf(h, w2n, delta1);
        }
    }

    const float b2v = b2p[0];
    float* op = sout + (((long)b * HGT + y) * WID + x0) * 3;
#pragma unroll
    for (int p = 0; p < 2; ++p) {
        const float s0 = X[1][p + 1][0];
        const float d  = (p == 0 ? delta0 : delta1) + b2v;   // + b2 (zero)
        const float td = ALPHA * d;              // exact (exponent shift)
        float pat = s0 + td;                     // f32 add
        pat = fminf(fmaxf(pat, 0.f), 1.f);       // clip
        op[p * 3 + 0] = pat;
        op[p * 3 + 1] = X[1][p + 1][1];
        op[p * 3 + 2] = X[1][p + 1][2];
    }
}

extern "C" void kernel_launch(void* const* d_in, const int* in_sizes, int n_in,
                              void* d_out, int out_size, void* d_ws, size_t ws_size,
                              hipStream_t stream) {
    const float* state = (const float*)d_in[0];
    const float* W1    = (const float*)d_in[1];
    const float* b1    = (const float*)d_in[2];
    const float* W2    = (const float*)d_in[3];
    const float* b2    = (const float*)d_in[4];

    float* ws_state = (float*)d_ws;
    float* w1t      = ws_state + WS_W1T_OFF;
    float* w2c      = ws_state + WS_W2_OFF;
    float* out      = (float*)d_out;

    nca_prep<<<1, 256, 0, stream>>>(W1, b1, W2, ws_state);

    const int nblocks = (BATCH * HGT * (WID / 2)) / 256;   // 1024

    for (int t = 0; t < 128; ++t) {
        const float* in  = (t == 0) ? state : (((t - 1) & 1) ? out : ws_state);
        float*       dst = (t & 1) ? out : ws_state;
        nca_step<<<nblocks, 256, 0, stream>>>(in, dst, w1t, w2c, b2);
    }
}